// Round 4
// baseline (463.381 us; speedup 1.0000x reference)
//
#include <hip/hip_runtime.h>
#include <hip/hip_bf16.h>

// Problem constants
#define BS 8
#define NN 64
#define HD 512
#define NLAYER 5
// Inputs are FLOAT32 (per reference dtypes); output fp32 (128 MB).
// Internally: bf16 copies of weights + es for MFMA. Big scratch lives in
// d_out (128 MB >> 75 MB needed); ws holds only nodef (1 MB) + denom.

typedef short bf16x8 __attribute__((ext_vector_type(8)));
typedef float f32x4 __attribute__((ext_vector_type(4)));

__device__ __forceinline__ float lrelu(float x) { return x > 0.f ? x : 0.01f * x; }

__device__ __forceinline__ void cp16(const void* g, void* l) {
    __builtin_amdgcn_global_load_lds(
        (const __attribute__((address_space(1))) unsigned int*)g,
        (__attribute__((address_space(3))) unsigned int*)l,
        16, 0, 0);
}

// ---------------------------------------------------------------------------
// Convert node_W and edge_W (5 x 512 x 512 fp32 each) to bf16.
// blocks 0..1279 -> nW, 1280..2559 -> eW; 1024 elems/block.
__global__ __launch_bounds__(256) void wcvt_kernel(
    const float* __restrict__ nW, const float* __restrict__ eW,
    __hip_bfloat16* __restrict__ nWb, __hip_bfloat16* __restrict__ eWb)
{
    int bid = blockIdx.x;
    const float* src = (bid < 1280) ? nW : eW;
    __hip_bfloat16* dst = (bid < 1280) ? nWb : eWb;
    int base = (bid & 1279 % 1280, (bid < 1280 ? bid : bid - 1280)) * 1024 + threadIdx.x * 4;
#pragma unroll
    for (int k = 0; k < 4; ++k) dst[base + k] = __float2bfloat16(src[base + k]);
}

// ---------------------------------------------------------------------------
// prep: node_state fp32 + bf16 shadow; edge_init = mean(img, HW); denom
__global__ __launch_bounds__(256) void prep_kernel(
    const float* __restrict__ roi,
    const float* __restrict__ img,
    const int* __restrict__ mask,
    float* __restrict__ nodef, __hip_bfloat16* __restrict__ nodeb,
    float* __restrict__ edge_init, float* __restrict__ denom)
{
    int bid = blockIdx.x, tid = threadIdx.x;
    if (bid < 256) {
        int base = bid * 1024 + tid * 4;
#pragma unroll
        for (int k = 0; k < 4; ++k) {
            float v = roi[base + k];
            nodef[base + k] = v;
            nodeb[base + k] = __float2bfloat16(v);
        }
    } else if (bid < 256 + 1024) {
        int pid = (bid - 256) * 4 + (tid >> 6);   // (b*512+h), 0..4095
        int l = tid & 63;
        const float* p = img + (size_t)pid * 196;
        float s = 0.f;
        for (int x = l; x < 196; x += 64) s += p[x];
#pragma unroll
        for (int off = 1; off < 64; off <<= 1) s += __shfl_xor(s, off, 64);
        if (l == 0) edge_init[pid] = s * (1.f / 196.f);
    } else {
        int pid = (bid - 1280) * 256 + tid;       // 0..511
        if (pid < 512) {
            const int* m = mask + pid * 64;
            int s = 0;
#pragma unroll
            for (int j = 0; j < 64; ++j) s += m[j];
            denom[pid] = (float)s + 1.f;
        }
    }
}

// ---------------------------------------------------------------------------
// em0[b][o] = dot(edge_init[b][:], edge_W0[o][:]) + edge_b0[o]   (all fp32)
__global__ __launch_bounds__(256) void em0_kernel(
    const float* __restrict__ edge_init,
    const float* __restrict__ eW0,
    const float* __restrict__ eB0,
    float* __restrict__ em0)
{
    int t = blockIdx.x * 256 + threadIdx.x;   // 0..4095
    int b = t >> 9, o = t & 511;
    const float* ei = edge_init + b * 512;
    const float* w = eW0 + (size_t)o * 512;
    float s = eB0[o];
#pragma unroll 8
    for (int h = 0; h < 512; ++h) s += ei[h] * w[h];
    em0[t] = s;
}

// ---------------------------------------------------------------------------
// nm GEMM: nm[r][o] = sum_h node_bf16[r][h] * W[o][h] + bias[o]  (512x512x512)
__global__ __launch_bounds__(256) void nm_gemm(
    const __hip_bfloat16* __restrict__ A,   // 512x512 node bf16
    const __hip_bfloat16* __restrict__ W,   // 512x512 (o,h) bf16
    const float* __restrict__ bias,
    float* __restrict__ nm)
{
    __shared__ __align__(16) __hip_bfloat16 sA[64 * 32];
    __shared__ __align__(16) __hip_bfloat16 sB[64 * 32];
    int tid = threadIdx.x;
    int bm = blockIdx.x, bn = blockIdx.y;
    int w = tid >> 6, l = tid & 63;
    int lq = l >> 4, lr = l & 15;

    const char* aBase = (const char*)A + (size_t)bm * 64 * 1024;  // row stride 1024B
    const char* bBase = (const char*)W + (size_t)bn * 64 * 1024;
    int offG = (tid >> 2) * 1024 + (tid & 3) * 16;
    int offL = tid * 16;

    f32x4 acc[4] = {};

    for (int kt = 0; kt < 16; ++kt) {
        int ko = kt * 64;
        cp16(aBase + offG + ko, (char*)sA + offL);
        cp16(bBase + offG + ko, (char*)sB + offL);
        __syncthreads();
        bf16x8 af = *(const bf16x8*)&sA[(w * 16 + lr) * 32 + lq * 8];
#pragma unroll
        for (int ni = 0; ni < 4; ++ni) {
            bf16x8 bfv = *(const bf16x8*)&sB[(ni * 16 + lr) * 32 + lq * 8];
            acc[ni] = __builtin_amdgcn_mfma_f32_16x16x32_bf16(af, bfv, acc[ni], 0, 0, 0);
        }
        __syncthreads();
    }
#pragma unroll
    for (int ni = 0; ni < 4; ++ni) {
        int col = bn * 64 + ni * 16 + lr;
        float bv = bias[col];
#pragma unroll
        for (int r = 0; r < 4; ++r) {
            int row = bm * 64 + w * 16 + lq * 4 + r;
            nm[(size_t)row * 512 + col] = acc[ni][r] + bv;
        }
    }
}

// ---------------------------------------------------------------------------
// t=0 edge pass (em is rank-1): es = lrelu(nm_i + nm_j + em0_b)
__global__ __launch_bounds__(256) void edge_rank1(
    const float* __restrict__ nm, const float* __restrict__ em0,
    const int* __restrict__ mask,
    __hip_bfloat16* __restrict__ es_dst, float* __restrict__ agg)
{
    int g = blockIdx.x >> 1, ch = blockIdx.x & 1;
    int w = threadIdx.x >> 6, l = threadIdx.x & 63;
    int c = ch * 256 + w * 64 + l;
    int b = g >> 6;
    float nmi = nm[(size_t)g * 512 + c];
    float emb = em0[b * 512 + c];
    const float* nmb = nm + (size_t)b * 64 * 512;
    const int* mrow = mask + g * 64;
    __hip_bfloat16* erow = es_dst + (size_t)g * 64 * 512 + c;
    float aggv = 0.f;
#pragma unroll 4
    for (int j = 0; j < 64; ++j) {
        float nmj = nmb[j * 512 + c];
        float es = lrelu(nmi + nmj + emb);
        erow[(size_t)j * 512] = __float2bfloat16(es);
        aggv += es * nmj * (float)mrow[j];
    }
    agg[(size_t)g * 512 + c] = aggv;
}

// ---------------------------------------------------------------------------
// Fused edge GEMM + epilogue for t>=1.  BM=BN=128, BK=32.
__global__ __launch_bounds__(256) void edge_fused(
    const __hip_bfloat16* __restrict__ es_src,   // 32768 x 512 bf16
    const __hip_bfloat16* __restrict__ eW,       // 512 x 512 bf16 (o,h)
    const float* __restrict__ eB,                // 512 fp32
    const float* __restrict__ nm,                // 512 x 512 fp32
    const int* __restrict__ mask,                // 8*64*64
    __hip_bfloat16* __restrict__ es_dst,
    float* __restrict__ agg,
    int write_es)
{
    __shared__ __align__(16) __hip_bfloat16 sA[128 * 32];
    __shared__ __align__(16) __hip_bfloat16 sB[128 * 32];
    int tid = threadIdx.x;
    int bm = blockIdx.x, bn = blockIdx.y;
    int w = tid >> 6, l = tid & 63;
    int wm = w >> 1, wn = w & 1;
    int lq = l >> 4, lr = l & 15;

    const char* aBase = (const char*)es_src + (size_t)bm * 128 * 1024;
    const char* bBase = (const char*)eW + (size_t)bn * 128 * 1024;
    int offG = (tid >> 2) * 1024 + (tid & 3) * 16;  // rows 0..63
    int offL = tid * 16;

    f32x4 acc[4][4] = {};

    for (int kt = 0; kt < 16; ++kt) {
        int ko = kt * 64;
        cp16(aBase + offG + ko,         (char*)sA + offL);
        cp16(aBase + offG + 65536 + ko, (char*)sA + offL + 4096);  // rows 64..127
        cp16(bBase + offG + ko,         (char*)sB + offL);
        cp16(bBase + offG + 65536 + ko, (char*)sB + offL + 4096);
        __syncthreads();
        bf16x8 af[4], bfv[4];
#pragma unroll
        for (int mi = 0; mi < 4; ++mi)
            af[mi] = *(const bf16x8*)&sA[(wm * 64 + mi * 16 + lr) * 32 + lq * 8];
#pragma unroll
        for (int ni = 0; ni < 4; ++ni)
            bfv[ni] = *(const bf16x8*)&sB[(wn * 64 + ni * 16 + lr) * 32 + lq * 8];
#pragma unroll
        for (int mi = 0; mi < 4; ++mi)
#pragma unroll
            for (int ni = 0; ni < 4; ++ni)
                acc[mi][ni] = __builtin_amdgcn_mfma_f32_16x16x32_bf16(af[mi], bfv[ni], acc[mi][ni], 0, 0, 0);
        __syncthreads();
    }

    // Epilogue: wave owns group g = bm*2+wm (all 64 j) x 64 cols
    int g = bm * 2 + wm;            // = b*64 + i
    int b = g >> 6;
    int cbase = bn * 128 + wn * 64;

    float nmi[4];
#pragma unroll
    for (int ni = 0; ni < 4; ++ni) {
        int c = cbase + ni * 16 + lr;
        nmi[ni] = nm[(size_t)g * 512 + c] + eB[c];
    }
    const float* nmb = nm + (size_t)b * 64 * 512;
    const int* mrow = mask + g * 64;
    float aggv[4] = {0.f, 0.f, 0.f, 0.f};

#pragma unroll
    for (int mi = 0; mi < 4; ++mi) {
#pragma unroll
        for (int r = 0; r < 4; ++r) {
            int j = mi * 16 + lq * 4 + r;
            float mf = (float)mrow[j];
            const float* nrow = nmb + (size_t)j * 512;
            size_t erow = ((size_t)(g * 64 + j)) * 512;
#pragma unroll
            for (int ni = 0; ni < 4; ++ni) {
                int c = cbase + ni * 16 + lr;
                float nmj = nrow[c];
                float es = lrelu(acc[mi][ni][r] + nmi[ni] + nmj);
                if (write_es) es_dst[erow + c] = __float2bfloat16(es);
                aggv[ni] += es * nmj * mf;
            }
        }
    }
#pragma unroll
    for (int ni = 0; ni < 4; ++ni) {
        float v = aggv[ni];
        v += __shfl_xor(v, 16, 64);
        v += __shfl_xor(v, 32, 64);
        if (lq == 0) agg[(size_t)g * 512 + cbase + ni * 16 + lr] = v;
    }
}

// ---------------------------------------------------------------------------
// node_state += lrelu((nm + agg)/denom); refresh bf16 shadow
__global__ __launch_bounds__(256) void node_update(
    const float* __restrict__ nm, const float* __restrict__ agg,
    const float* __restrict__ denom,
    float* __restrict__ nodef, __hip_bfloat16* __restrict__ nodeb)
{
    int idx = blockIdx.x * 256 + threadIdx.x;   // 262144
    int g = idx >> 9;
    float nf = (nm[idx] + agg[idx]) / denom[g];
    float ns = nodef[idx] + lrelu(nf);
    nodef[idx] = ns;
    nodeb[idx] = __float2bfloat16(ns);
}

// ---------------------------------------------------------------------------
// out (fp32): out[b,i,j,0:512]=node[b,i,:], [512:1024]=node[b,j,:]
// 33,554,432 fp32 = 8,388,608 16B chunks -> 32768 blocks
__global__ __launch_bounds__(256) void out_kernel(
    const float* __restrict__ nodef, float* __restrict__ out)
{
    size_t ch = (size_t)blockIdx.x * 256 + threadIdx.x;  // 16B chunk id
    int c4 = (int)(ch & 255);          // 256 chunks per 1024-float row
    size_t r = ch >> 8;                // (b*64+i)*64 + j, 0..32767
    int b = (int)(r >> 12);
    int i = (int)((r >> 6) & 63);
    int j = (int)(r & 63);
    int c = c4 * 4;
    const float* src = (c < 512) ? (nodef + ((size_t)(b * 64 + i)) * 512 + c)
                                 : (nodef + ((size_t)(b * 64 + j)) * 512 + (c - 512));
    *reinterpret_cast<float4*>(out + ch * 4) = *reinterpret_cast<const float4*>(src);
}

// ---------------------------------------------------------------------------
extern "C" void kernel_launch(void* const* d_in, const int* in_sizes, int n_in,
                              void* d_out, int out_size, void* d_ws, size_t ws_size,
                              hipStream_t stream) {
    const float* roi  = (const float*)d_in[0];
    const float* img  = (const float*)d_in[1];
    const float* nW   = (const float*)d_in[2];
    const float* nB   = (const float*)d_in[3];
    const float* eW   = (const float*)d_in[4];
    const float* eB   = (const float*)d_in[5];
    const int*   mask = (const int*)d_in[6];

    // Large scratch inside d_out (128 MB fp32 out; we use first ~75 MB).
    // out_kernel only reads nodef (in ws), so rewriting d_out at the end is safe.
    char* ob = (char*)d_out;
    const size_t ES_BYTES = (size_t)32768 * 512 * 2;            // 33,554,432
    __hip_bfloat16* es0   = (__hip_bfloat16*)(ob);
    __hip_bfloat16* es1   = (__hip_bfloat16*)(ob + ES_BYTES);
    __hip_bfloat16* eWb   = (__hip_bfloat16*)(ob + 2 * ES_BYTES);              // 2.62MB
    __hip_bfloat16* nWb   = (__hip_bfloat16*)(ob + 2 * ES_BYTES + 2621440);    // 2.62MB
    __hip_bfloat16* nodeb = (__hip_bfloat16*)(ob + 2 * ES_BYTES + 5242880);    // 0.5MB
    float*          nm    = (float*)(ob + 2 * ES_BYTES + 5767168);             // 1MB
    float*          agg   = (float*)(ob + 2 * ES_BYTES + 6815744);             // 1MB
    float*       edge_init= (float*)(ob + 2 * ES_BYTES + 7864320);             // 16KB
    float*          em0   = (float*)(ob + 2 * ES_BYTES + 7880704);             // 16KB

    char* ws = (char*)d_ws;
    float* nodef = (float*)(ws);                 // 1MB
    float* denom = (float*)(ws + 1048576);       // 2KB
    float* outp  = (float*)d_out;

    wcvt_kernel<<<2560, 256, 0, stream>>>(nW, eW, nWb, eWb);
    prep_kernel<<<1282, 256, 0, stream>>>(roi, img, mask, nodef, nodeb, edge_init, denom);
    em0_kernel<<<16, 256, 0, stream>>>(edge_init, eW, eB, em0);

    // t = 0
    nm_gemm<<<dim3(8, 8), 256, 0, stream>>>(nodeb, nWb, nB, nm);
    edge_rank1<<<1024, 256, 0, stream>>>(nm, em0, mask, es0, agg);
    node_update<<<1024, 256, 0, stream>>>(nm, agg, denom, nodef, nodeb);

    // t = 1..4
    for (int t = 1; t < NLAYER; ++t) {
        const __hip_bfloat16* src = (t & 1) ? es0 : es1;
        __hip_bfloat16* dst       = (t & 1) ? es1 : es0;
        nm_gemm<<<dim3(8, 8), 256, 0, stream>>>(nodeb, nWb + (size_t)t * 262144,
                                                nB + t * 512, nm);
        edge_fused<<<dim3(256, 4), 256, 0, stream>>>(src, eWb + (size_t)t * 262144,
                                                     eB + t * 512, nm, mask,
                                                     dst, agg, (t < 4) ? 1 : 0);
        node_update<<<1024, 256, 0, stream>>>(nm, agg, denom, nodef, nodeb);
    }

    out_kernel<<<32768, 256, 0, stream>>>(nodef, outp);
}

// Round 5
// 425.390 us; speedup vs baseline: 1.0893x; 1.0893x over previous
//
#include <hip/hip_runtime.h>
#include <hip/hip_bf16.h>

// Problem constants
#define BS 8
#define NN 64
#define HD 512
#define NLAYER 5
// Inputs fp32, output fp32 (128 MB). bf16 internally for MFMA.
// Big scratch lives in d_out (~74 MB of 128 MB); ws holds nodef + denom only
// (out_kernel reads nodef while rewriting d_out).

typedef short bf16x8 __attribute__((ext_vector_type(8)));
typedef float f32x4 __attribute__((ext_vector_type(4)));

__device__ __forceinline__ float lrelu(float x) { return x > 0.f ? x : 0.01f * x; }

__device__ __forceinline__ void cp16(const void* g, void* l) {
    __builtin_amdgcn_global_load_lds(
        (const __attribute__((address_space(1))) unsigned int*)g,
        (__attribute__((address_space(3))) unsigned int*)l,
        16, 0, 0);
}

// ---------------------------------------------------------------------------
// prep (fused wcvt + node init + edge_init + denom):
// blocks 0..1279   : nW -> nWb (1024 elems/blk)
// blocks 1280..2559: eW -> eWb
// blocks 2560..2815: roi -> nodef (fp32) + nodeb (bf16)
// blocks 2816..3839: edge_init = mean(img, HW)  (4 (b,h) pairs per block)
// blocks 3840..3841: denom
__global__ __launch_bounds__(256) void prep_kernel(
    const float* __restrict__ roi, const float* __restrict__ img,
    const float* __restrict__ nW, const float* __restrict__ eW,
    const int* __restrict__ mask,
    __hip_bfloat16* __restrict__ nWb, __hip_bfloat16* __restrict__ eWb,
    float* __restrict__ nodef, __hip_bfloat16* __restrict__ nodeb,
    float* __restrict__ edge_init, float* __restrict__ denom)
{
    int bid = blockIdx.x, tid = threadIdx.x;
    if (bid < 2560) {
        const float* src = (bid < 1280) ? nW : eW;
        __hip_bfloat16* dst = (bid < 1280) ? nWb : eWb;
        int base = ((bid < 1280) ? bid : bid - 1280) * 1024 + tid * 4;
#pragma unroll
        for (int k = 0; k < 4; ++k) dst[base + k] = __float2bfloat16(src[base + k]);
    } else if (bid < 2816) {
        int base = (bid - 2560) * 1024 + tid * 4;
#pragma unroll
        for (int k = 0; k < 4; ++k) {
            float v = roi[base + k];
            nodef[base + k] = v;
            nodeb[base + k] = __float2bfloat16(v);
        }
    } else if (bid < 3840) {
        int pid = (bid - 2816) * 4 + (tid >> 6);   // (b*512+h), 0..4095
        int l = tid & 63;
        const float* p = img + (size_t)pid * 196;
        float s = 0.f;
        for (int x = l; x < 196; x += 64) s += p[x];
#pragma unroll
        for (int off = 1; off < 64; off <<= 1) s += __shfl_xor(s, off, 64);
        if (l == 0) edge_init[pid] = s * (1.f / 196.f);
    } else {
        int pid = (bid - 3840) * 256 + tid;       // 0..511
        if (pid < 512) {
            const int* m = mask + pid * 64;
            int s = 0;
#pragma unroll
            for (int j = 0; j < 64; ++j) s += m[j];
            denom[pid] = (float)s + 1.f;
        }
    }
}

// ---------------------------------------------------------------------------
// em0: one wave per (b,o). Coalesced float4 loads of eW0 row, shuffle-reduce.
__global__ __launch_bounds__(256) void em0_kernel(
    const float* __restrict__ edge_init,
    const float* __restrict__ eW0,
    const float* __restrict__ eB0,
    float* __restrict__ em0)
{
    int W = blockIdx.x * 4 + (threadIdx.x >> 6);  // 0..4095
    int l = threadIdx.x & 63;
    int b = W >> 9, o = W & 511;
    const float4* ei = (const float4*)(edge_init + b * 512);
    const float4* w4 = (const float4*)(eW0 + (size_t)o * 512);
    float4 a0 = ei[l * 2], a1 = ei[l * 2 + 1];
    float4 b0 = w4[l * 2], b1 = w4[l * 2 + 1];
    float s = a0.x * b0.x + a0.y * b0.y + a0.z * b0.z + a0.w * b0.w
            + a1.x * b1.x + a1.y * b1.y + a1.z * b1.z + a1.w * b1.w;
#pragma unroll
    for (int off = 1; off < 64; off <<= 1) s += __shfl_xor(s, off, 64);
    if (l == 0) em0[W] = s + eB0[o];
}

// ---------------------------------------------------------------------------
// nm GEMM: nm[r][o] = sum_h node_bf16[r][h] * W[o][h] + bias[o]  (512x512x512)
__global__ __launch_bounds__(256) void nm_gemm(
    const __hip_bfloat16* __restrict__ A,   // 512x512 node bf16
    const __hip_bfloat16* __restrict__ W,   // 512x512 (o,h) bf16
    const float* __restrict__ bias,
    float* __restrict__ nm)
{
    __shared__ __align__(16) __hip_bfloat16 sA[64 * 32];
    __shared__ __align__(16) __hip_bfloat16 sB[64 * 32];
    int tid = threadIdx.x;
    int bm = blockIdx.x, bn = blockIdx.y;
    int w = tid >> 6, l = tid & 63;
    int lq = l >> 4, lr = l & 15;

    const char* aBase = (const char*)A + (size_t)bm * 64 * 1024;  // row stride 1024B
    const char* bBase = (const char*)W + (size_t)bn * 64 * 1024;
    int offG = (tid >> 2) * 1024 + (tid & 3) * 16;
    int offL = tid * 16;

    f32x4 acc[4] = {};

    for (int kt = 0; kt < 16; ++kt) {
        int ko = kt * 64;
        cp16(aBase + offG + ko, (char*)sA + offL);
        cp16(bBase + offG + ko, (char*)sB + offL);
        __syncthreads();
        bf16x8 af = *(const bf16x8*)&sA[(w * 16 + lr) * 32 + lq * 8];
#pragma unroll
        for (int ni = 0; ni < 4; ++ni) {
            bf16x8 bfv = *(const bf16x8*)&sB[(ni * 16 + lr) * 32 + lq * 8];
            acc[ni] = __builtin_amdgcn_mfma_f32_16x16x32_bf16(af, bfv, acc[ni], 0, 0, 0);
        }
        __syncthreads();
    }
#pragma unroll
    for (int ni = 0; ni < 4; ++ni) {
        int col = bn * 64 + ni * 16 + lr;
        float bv = bias[col];
#pragma unroll
        for (int r = 0; r < 4; ++r) {
            int row = bm * 64 + w * 16 + lq * 4 + r;
            nm[(size_t)row * 512 + col] = acc[ni][r] + bv;
        }
    }
}

// ---------------------------------------------------------------------------
// t=0: es = lrelu(nm_i + nm_j + em0_b), write es, agg -> fused node update
__global__ __launch_bounds__(256) void edge_rank1(
    const float* __restrict__ nm, const float* __restrict__ em0,
    const int* __restrict__ mask,
    __hip_bfloat16* __restrict__ es_dst,
    const float* __restrict__ denom,
    float* __restrict__ nodef, __hip_bfloat16* __restrict__ nodeb)
{
    int g = blockIdx.x >> 1, ch = blockIdx.x & 1;
    int w = threadIdx.x >> 6, l = threadIdx.x & 63;
    int c = ch * 256 + w * 64 + l;
    int b = g >> 6;
    float nmi = nm[(size_t)g * 512 + c];          // raw nm[g][c]
    float emb = em0[b * 512 + c];
    const float* nmb = nm + (size_t)b * 64 * 512;
    const int* mrow = mask + g * 64;
    __hip_bfloat16* erow = es_dst + (size_t)g * 64 * 512 + c;
    float aggv = 0.f;
#pragma unroll 4
    for (int j = 0; j < 64; ++j) {
        float nmj = nmb[j * 512 + c];
        float es = lrelu(nmi + nmj + emb);
        erow[(size_t)j * 512] = __float2bfloat16(es);
        aggv += es * nmj * (float)mrow[j];
    }
    // fused node update (thread owns (g,c))
    float nf = (nmi + aggv) / denom[g];
    size_t idx = (size_t)g * 512 + c;
    float ns = nodef[idx] + lrelu(nf);
    nodef[idx] = ns;
    nodeb[idx] = __float2bfloat16(ns);
}

// ---------------------------------------------------------------------------
// Fused edge GEMM + epilogue + node update for t>=1.  BM=BN=128, BK=64.
// 4 waves: wm = row-half (one (b,i) group per wave), wn = col-half.
__global__ __launch_bounds__(256) void edge_fused(
    const __hip_bfloat16* __restrict__ es_src,   // 32768 x 512 bf16
    const __hip_bfloat16* __restrict__ eW,       // 512 x 512 bf16 (o,h)
    const float* __restrict__ eB,                // 512 fp32
    const float* __restrict__ nm,                // 512 x 512 fp32
    const int* __restrict__ mask,                // 8*64*64
    __hip_bfloat16* __restrict__ es_dst,
    const float* __restrict__ denom,
    float* __restrict__ nodef, __hip_bfloat16* __restrict__ nodeb,
    int write_es)
{
    __shared__ __align__(16) __hip_bfloat16 sA[128 * 64];   // 16 KB
    __shared__ __align__(16) __hip_bfloat16 sB[128 * 64];   // 16 KB
    int tid = threadIdx.x;
    int bn = blockIdx.x, bm = blockIdx.y;    // bn fastest: 4 blocks share A-tile
    int w = tid >> 6, l = tid & 63;
    int wm = w >> 1, wn = w & 1;
    int lq = l >> 4, lr = l & 15;

    const char* aBase = (const char*)es_src + (size_t)bm * 128 * 1024;  // row 1024B
    const char* bBase = (const char*)eW + (size_t)bn * 128 * 1024;
    // staging: 1024 16B-chunks per matrix per kt; thread t -> chunks t+i*256
    // chunk c: row = c>>3, col16 = c&7 ; global row*1024 + (c&7)*16 ; lds c*16
    int gOff = (tid >> 3) * 1024 + (tid & 7) * 16;
    int lOff = tid * 16;

    f32x4 acc[4][4] = {};

    for (int kt = 0; kt < 8; ++kt) {
        int ko = kt * 128;   // 64 cols * 2B
#pragma unroll
        for (int i = 0; i < 4; ++i) {
            cp16(aBase + gOff + i * 32768 + ko, (char*)sA + lOff + i * 4096);
            cp16(bBase + gOff + i * 32768 + ko, (char*)sB + lOff + i * 4096);
        }
        __syncthreads();
#pragma unroll
        for (int kk = 0; kk < 2; ++kk) {
            bf16x8 af[4], bfv[4];
#pragma unroll
            for (int mi = 0; mi < 4; ++mi)
                af[mi] = *(const bf16x8*)&sA[(wm * 64 + mi * 16 + lr) * 64 + kk * 32 + lq * 8];
#pragma unroll
            for (int ni = 0; ni < 4; ++ni)
                bfv[ni] = *(const bf16x8*)&sB[(wn * 64 + ni * 16 + lr) * 64 + kk * 32 + lq * 8];
#pragma unroll
            for (int mi = 0; mi < 4; ++mi)
#pragma unroll
                for (int ni = 0; ni < 4; ++ni)
                    acc[mi][ni] = __builtin_amdgcn_mfma_f32_16x16x32_bf16(af[mi], bfv[ni], acc[mi][ni], 0, 0, 0);
        }
        __syncthreads();
    }

    // Epilogue: wave owns group g = bm*2+wm (all 64 j) x 64 cols
    int g = bm * 2 + wm;            // = b*64 + i
    int b = g >> 6;
    int cbase = bn * 128 + wn * 64;

    float nmraw[4], nmi[4];
#pragma unroll
    for (int ni = 0; ni < 4; ++ni) {
        int c = cbase + ni * 16 + lr;
        nmraw[ni] = nm[(size_t)g * 512 + c];
        nmi[ni] = nmraw[ni] + eB[c];
    }
    const float* nmb = nm + (size_t)b * 64 * 512;
    const int* mrow = mask + g * 64;
    float aggv[4] = {0.f, 0.f, 0.f, 0.f};

#pragma unroll
    for (int mi = 0; mi < 4; ++mi) {
#pragma unroll
        for (int r = 0; r < 4; ++r) {
            int j = mi * 16 + lq * 4 + r;
            float mf = (float)mrow[j];
            const float* nrow = nmb + (size_t)j * 512;
            size_t erow = ((size_t)(g * 64 + j)) * 512;
#pragma unroll
            for (int ni = 0; ni < 4; ++ni) {
                int c = cbase + ni * 16 + lr;
                float nmj = nrow[c];
                float es = lrelu(acc[mi][ni][r] + nmi[ni] + nmj);
                if (write_es) es_dst[erow + c] = __float2bfloat16(es);
                aggv[ni] += es * nmj * mf;
            }
        }
    }
    float dinv = denom[g];
#pragma unroll
    for (int ni = 0; ni < 4; ++ni) {
        float v = aggv[ni];
        v += __shfl_xor(v, 16, 64);
        v += __shfl_xor(v, 32, 64);
        if (lq == 0) {
            size_t idx = (size_t)g * 512 + cbase + ni * 16 + lr;
            float nf = (nmraw[ni] + v) / dinv;
            float ns = nodef[idx] + lrelu(nf);
            nodef[idx] = ns;
            nodeb[idx] = __float2bfloat16(ns);
        }
    }
}

// ---------------------------------------------------------------------------
// out (fp32): out[b,i,j,0:512]=node[b,i,:], [512:1024]=node[b,j,:]
// 33,554,432 fp32 = 8,388,608 16B chunks -> 32768 blocks
__global__ __launch_bounds__(256) void out_kernel(
    const float* __restrict__ nodef, float* __restrict__ out)
{
    size_t ch = (size_t)blockIdx.x * 256 + threadIdx.x;  // 16B chunk id
    int c4 = (int)(ch & 255);          // 256 chunks per 1024-float row
    size_t r = ch >> 8;                // (b*64+i)*64 + j
    int b = (int)(r >> 12);
    int i = (int)((r >> 6) & 63);
    int j = (int)(r & 63);
    int c = c4 * 4;
    const float* src = (c < 512) ? (nodef + ((size_t)(b * 64 + i)) * 512 + c)
                                 : (nodef + ((size_t)(b * 64 + j)) * 512 + (c - 512));
    *reinterpret_cast<float4*>(out + ch * 4) = *reinterpret_cast<const float4*>(src);
}

// ---------------------------------------------------------------------------
extern "C" void kernel_launch(void* const* d_in, const int* in_sizes, int n_in,
                              void* d_out, int out_size, void* d_ws, size_t ws_size,
                              hipStream_t stream) {
    const float* roi  = (const float*)d_in[0];
    const float* img  = (const float*)d_in[1];
    const float* nW   = (const float*)d_in[2];
    const float* nB   = (const float*)d_in[3];
    const float* eW   = (const float*)d_in[4];
    const float* eB   = (const float*)d_in[5];
    const int*   mask = (const int*)d_in[6];

    // Large scratch inside d_out (128 MB); all dead before out_kernel rewrites.
    char* ob = (char*)d_out;
    const size_t ES_BYTES = (size_t)32768 * 512 * 2;            // 33,554,432
    __hip_bfloat16* es0   = (__hip_bfloat16*)(ob);
    __hip_bfloat16* es1   = (__hip_bfloat16*)(ob + ES_BYTES);
    __hip_bfloat16* eWb   = (__hip_bfloat16*)(ob + 2 * ES_BYTES);              // 2.62MB
    __hip_bfloat16* nWb   = (__hip_bfloat16*)(ob + 2 * ES_BYTES + 2621440);    // 2.62MB
    __hip_bfloat16* nodeb = (__hip_bfloat16*)(ob + 2 * ES_BYTES + 5242880);    // 0.5MB
    float*          nm    = (float*)(ob + 2 * ES_BYTES + 5767168);             // 1MB
    float*       edge_init= (float*)(ob + 2 * ES_BYTES + 6815744);             // 16KB
    float*          em0   = (float*)(ob + 2 * ES_BYTES + 6832128);             // 16KB

    char* ws = (char*)d_ws;
    float* nodef = (float*)(ws);                 // 1MB
    float* denom = (float*)(ws + 1048576);       // 2KB
    float* outp  = (float*)d_out;

    prep_kernel<<<3842, 256, 0, stream>>>(roi, img, nW, eW, mask,
                                          nWb, eWb, nodef, nodeb, edge_init, denom);
    em0_kernel<<<1024, 256, 0, stream>>>(edge_init, eW, eB, em0);

    // t = 0
    nm_gemm<<<dim3(8, 8), 256, 0, stream>>>(nodeb, nWb, nB, nm);
    edge_rank1<<<1024, 256, 0, stream>>>(nm, em0, mask, es0, denom, nodef, nodeb);

    // t = 1..4
    for (int t = 1; t < NLAYER; ++t) {
        const __hip_bfloat16* src = (t & 1) ? es0 : es1;
        __hip_bfloat16* dst       = (t & 1) ? es1 : es0;
        nm_gemm<<<dim3(8, 8), 256, 0, stream>>>(nodeb, nWb + (size_t)t * 262144,
                                                nB + t * 512, nm);
        edge_fused<<<dim3(4, 256), 256, 0, stream>>>(src, eWb + (size_t)t * 262144,
                                                     eB + t * 512, nm, mask,
                                                     dst, denom, nodef, nodeb,
                                                     (t < 4) ? 1 : 0);
    }

    out_kernel<<<32768, 256, 0, stream>>>(nodef, outp);
}